// Round 2
// baseline (264.839 us; speedup 1.0000x reference)
//
#include <hip/hip_runtime.h>
#include <math.h>

// Capsule routing, fused. B=64, I=1024, O=1024 fp32.
//
// Math reduction: b after iter k equals u_hat * (v1+..+vk)[:,None,:], so
// c_k = softmax_o(u[b,i]*w[i,o]*vsum[b,o]). No [B,I,O] tensor needed.
//
// Stage kernel: one wave owns 2 softmax rows (b0,i),(b1,i) at a time.
// Lane L holds o = j*256 + L*4 + e (j,e in 0..3): coalesced float4 w loads.
// No wave_max: |u*w*v| <= ~0.3, exp cannot overflow (absmax headroom 75x).
// Two batches per block: w-row regs reused 2x (halves L2 traffic) and the
// two exp+shuffle-reduce chains are independent -> ILP hides DS latency.
// Block partials go through an 8KB LDS cross-wave reduce, then plain
// coalesced float4 stores to per-iblk slices (NO global atomics, NO memsets).

#define BB 64
#define II 1024
#define OO 1024
#define EPSF 1e-5f

__device__ __forceinline__ float wave_sum(float v) {
    #pragma unroll
    for (int off = 32; off > 0; off >>= 1)
        v += __shfl_xor(v, off, 64);
    return v;
}
__device__ __forceinline__ void wave_sum2(float& a, float& b) {
    #pragma unroll
    for (int off = 32; off > 0; off >>= 1) {
        a += __shfl_xor(a, off, 64);   // two independent chains ->
        b += __shfl_xor(b, off, 64);   // compiler interleaves them
    }
}

// Cross-wave reduce of the 4 waves' ar[16] (same o-mapping per wave) via
// LDS float-atomics (bank-conflict-free: addr/4 = k*64+lane -> 2-way, free),
// then coalesced float4 partial store. LDS layout idx = (j*4+e)*64 + lane
// for o = j*256 + lane*4 + e.
__device__ __forceinline__ void block_reduce_store(
    float* red, const float (&ar0)[16], const float (&ar1)[16], int lane,
    float* __restrict__ part_b0, float* __restrict__ part_b1)
{
    const int t = threadIdx.x;
    for (int r = t; r < 2048; r += 256) red[r] = 0.f;
    __syncthreads();
    #pragma unroll
    for (int k = 0; k < 16; k++) {
        atomicAdd(&red[k * 64 + lane],        ar0[k]);
        atomicAdd(&red[1024 + k * 64 + lane], ar1[k]);
    }
    __syncthreads();
    // thread t writes o = 4t..4t+3: j = t>>6, lane-field = t&63, e = o&3
    const int j  = t >> 6;
    const int ln = t & 63;
    float4 v0, v1;
    v0.x = red[(j*4+0)*64 + ln]; v0.y = red[(j*4+1)*64 + ln];
    v0.z = red[(j*4+2)*64 + ln]; v0.w = red[(j*4+3)*64 + ln];
    v1.x = red[1024 + (j*4+0)*64 + ln]; v1.y = red[1024 + (j*4+1)*64 + ln];
    v1.z = red[1024 + (j*4+2)*64 + ln]; v1.w = red[1024 + (j*4+3)*64 + ln];
    ((float4*)part_b0)[t] = v0;
    ((float4*)part_b1)[t] = v1;
}

// part[iblk][b][o] += is replaced by: block (bg,iblk) OWNS slice (iblk, b0/b1).
template<int IBLKS>
__global__ __launch_bounds__(256) void stage_k(
    const float* __restrict__ u, const float* __restrict__ w,
    const float* __restrict__ v, float* __restrict__ part)
{
    constexpr int IPB = II / IBLKS;   // i's per block
    constexpr int IW  = IPB / 4;      // i's per wave
    const int bg   = blockIdx.x / IBLKS;
    const int iblk = blockIdx.x % IBLKS;
    const int wave = threadIdx.x >> 6;
    const int lane = threadIdx.x & 63;
    const int b0 = bg * 2, b1 = b0 + 1;
    const float4* w4  = (const float4*)w;
    const float4* v40 = (const float4*)(v + b0 * OO);
    const float4* v41 = (const float4*)(v + b1 * OO);

    float vv0[16], vv1[16];
    #pragma unroll
    for (int j = 0; j < 4; j++) {
        float4 a = v40[j * 64 + lane];
        float4 b = v41[j * 64 + lane];
        vv0[j*4+0]=a.x; vv0[j*4+1]=a.y; vv0[j*4+2]=a.z; vv0[j*4+3]=a.w;
        vv1[j*4+0]=b.x; vv1[j*4+1]=b.y; vv1[j*4+2]=b.z; vv1[j*4+3]=b.w;
    }
    float ar0[16], ar1[16];
    #pragma unroll
    for (int k = 0; k < 16; k++) { ar0[k] = 0.f; ar1[k] = 0.f; }

    const int i0 = iblk * IPB + wave * IW;
    #pragma unroll 2
    for (int ii = 0; ii < IW; ii++) {
        const int i = i0 + ii;
        const float ub0 = u[b0 * II + i];   // wave-uniform -> s_load
        const float ub1 = u[b1 * II + i];
        float wr[16];
        #pragma unroll
        for (int j = 0; j < 4; j++) {
            float4 t = w4[i * 256 + j * 64 + lane];
            wr[j*4+0]=t.x; wr[j*4+1]=t.y; wr[j*4+2]=t.z; wr[j*4+3]=t.w;
        }
        float p0[16], p1[16];
        float s0 = 0.f, s1 = 0.f;
        #pragma unroll
        for (int k = 0; k < 16; k++) {     // no max-subtract: |t| <= ~0.3
            p0[k] = __expf(ub0 * wr[k] * vv0[k]);
            p1[k] = __expf(ub1 * wr[k] * vv1[k]);
            s0 += p0[k]; s1 += p1[k];
        }
        wave_sum2(s0, s1);
        const float q0 = ub0 / s0;         // fold u scalar into 1/sum
        const float q1 = ub1 / s1;
        #pragma unroll
        for (int k = 0; k < 16; k++) {
            ar0[k] = fmaf(wr[k] * p0[k], q0, ar0[k]);
            ar1[k] = fmaf(wr[k] * p1[k], q1, ar1[k]);
        }
    }
    __shared__ float red[2048];
    block_reduce_store(red, ar0, ar1, lane,
        part + ((size_t)iblk * BB + b0) * OO,
        part + ((size_t)iblk * BB + b1) * OO);
}

// Plain partial GEMM: part slices of sum_i u*w (scale 1/O applied in squash).
template<int IBLKS>
__global__ __launch_bounds__(256) void gemm_k(
    const float* __restrict__ u, const float* __restrict__ w,
    float* __restrict__ part)
{
    constexpr int IPB = II / IBLKS;
    constexpr int IW  = IPB / 4;
    const int bg   = blockIdx.x / IBLKS;
    const int iblk = blockIdx.x % IBLKS;
    const int wave = threadIdx.x >> 6;
    const int lane = threadIdx.x & 63;
    const int b0 = bg * 2, b1 = b0 + 1;
    const float4* w4 = (const float4*)w;

    float ar0[16], ar1[16];
    #pragma unroll
    for (int k = 0; k < 16; k++) { ar0[k] = 0.f; ar1[k] = 0.f; }

    const int i0 = iblk * IPB + wave * IW;
    #pragma unroll 2
    for (int ii = 0; ii < IW; ii++) {
        const int i = i0 + ii;
        const float ub0 = u[b0 * II + i];
        const float ub1 = u[b1 * II + i];
        #pragma unroll
        for (int j = 0; j < 4; j++) {
            float4 t = w4[i * 256 + j * 64 + lane];
            ar0[j*4+0] = fmaf(ub0, t.x, ar0[j*4+0]);
            ar0[j*4+1] = fmaf(ub0, t.y, ar0[j*4+1]);
            ar0[j*4+2] = fmaf(ub0, t.z, ar0[j*4+2]);
            ar0[j*4+3] = fmaf(ub0, t.w, ar0[j*4+3]);
            ar1[j*4+0] = fmaf(ub1, t.x, ar1[j*4+0]);
            ar1[j*4+1] = fmaf(ub1, t.y, ar1[j*4+1]);
            ar1[j*4+2] = fmaf(ub1, t.z, ar1[j*4+2]);
            ar1[j*4+3] = fmaf(ub1, t.w, ar1[j*4+3]);
        }
    }
    __shared__ float red[2048];
    block_reduce_store(red, ar0, ar1, lane,
        part + ((size_t)iblk * BB + b0) * OO,
        part + ((size_t)iblk * BB + b1) * OO);
}

// Sum nblk partial slices, x = sum*scale + bias, squash row, emit:
// mode 0: vbuf = v   mode 1: vbuf += v   mode 2: out = v
__global__ __launch_bounds__(256) void reduce_squash(
    const float* __restrict__ part, const float* __restrict__ bias,
    float* __restrict__ vbuf, float* __restrict__ out,
    float scale, int mode, int nblk)
{
    const int b = blockIdx.x;
    const int t = threadIdx.x;
    const float4* p4 = (const float4*)part;

    float4 a = make_float4(0.f, 0.f, 0.f, 0.f);
    for (int k = 0; k < nblk; k++) {
        float4 p = p4[(size_t)(k * BB + b) * 256 + t];
        a.x += p.x; a.y += p.y; a.z += p.z; a.w += p.w;
    }
    float4 bb = ((const float4*)bias)[t];
    float4 x;
    x.x = fmaf(a.x, scale, bb.x); x.y = fmaf(a.y, scale, bb.y);
    x.z = fmaf(a.z, scale, bb.z); x.w = fmaf(a.w, scale, bb.w);

    float ss = x.x*x.x + x.y*x.y + x.z*x.z + x.w*x.w;
    ss = wave_sum(ss);
    __shared__ float red[4];
    if ((t & 63) == 0) red[t >> 6] = ss;
    __syncthreads();
    ss = red[0] + red[1] + red[2] + red[3];

    const float n  = sqrtf(ss);
    const float f  = ss / ((1.f + ss) * (n + EPSF));

    float4 vo;
    vo.x = x.x * f; vo.y = x.y * f; vo.z = x.z * f; vo.w = x.w * f;

    if (mode == 0) {
        ((float4*)(vbuf + b * OO))[t] = vo;
    } else if (mode == 1) {
        float4 pv = ((const float4*)(vbuf + b * OO))[t];
        pv.x += vo.x; pv.y += vo.y; pv.z += vo.z; pv.w += vo.w;
        ((float4*)(vbuf + b * OO))[t] = pv;
    } else {
        ((float4*)(out + b * OO))[t] = vo;
    }
}

template<int IBLKS>
static void run_pipeline(const float* u, const float* w, const float* bias,
                         float* out, void* d_ws, hipStream_t stream)
{
    float* part = (float*)d_ws;
    float* vbuf = part + (size_t)IBLKS * BB * OO;
    dim3 g((BB / 2) * IBLKS), blk(256);
    // v1 = squash((u@w)/O + bias)
    gemm_k<IBLKS><<<g, blk, 0, stream>>>(u, w, part);
    reduce_squash<<<dim3(BB), blk, 0, stream>>>(part, bias, vbuf, out,
                                                1.0f / (float)OO, 0, IBLKS);
    // vsum = v1 + squash(s2 + bias),  s2 via softmax(u*w*v1)
    stage_k<IBLKS><<<g, blk, 0, stream>>>(u, w, vbuf, part);
    reduce_squash<<<dim3(BB), blk, 0, stream>>>(part, bias, vbuf, out,
                                                1.0f, 1, IBLKS);
    // out = squash(s3 + bias),  s3 via softmax(u*w*vsum)
    stage_k<IBLKS><<<g, blk, 0, stream>>>(u, w, vbuf, part);
    reduce_squash<<<dim3(BB), blk, 0, stream>>>(part, bias, vbuf, out,
                                                1.0f, 2, IBLKS);
}

extern "C" void kernel_launch(void* const* d_in, const int* in_sizes, int n_in,
                              void* d_out, int out_size, void* d_ws, size_t ws_size,
                              hipStream_t stream) {
    (void)in_sizes; (void)n_in; (void)out_size;
    const float* u    = (const float*)d_in[0];
    const float* w    = (const float*)d_in[1];
    const float* bias = (const float*)d_in[2];
    float* out = (float*)d_out;

    const size_t row = (size_t)BB * OO * sizeof(float);  // 256 KB
    if      (ws_size >= 33 * row) run_pipeline<32>(u, w, bias, out, d_ws, stream);
    else if (ws_size >= 17 * row) run_pipeline<16>(u, w, bias, out, d_ws, stream);
    else if (ws_size >=  9 * row) run_pipeline<8>(u, w, bias, out, d_ws, stream);
    else                          run_pipeline<4>(u, w, bias, out, d_ws, stream);
}

// Round 3
// 262.233 us; speedup vs baseline: 1.0099x; 1.0099x over previous
//
#include <hip/hip_runtime.h>
#include <math.h>

// Capsule routing, fused. B=64, I=1024, O=1024 fp32.
//
// Math reduction: b after iter k equals u_hat * (v1+..+vk)[:,None,:], so
// c_k = softmax_o(u[b,i]*w[i,o]*vsum[b,o]). No [B,I,O] tensor needed.
//
// R2 lesson: default launch_bounds capped VGPR at 64 -> compiler serialized
// the whole iter into one dependence chain (latency-bound, VALUBusy 20%).
// R3: __launch_bounds__(256,4) -> 128 VGPR (grid is 4 blocks/CU = 4 waves/EU,
// so 4 min-waves/EU is exactly the occupancy we can reach anyway).
// Also: tree-sum the 16-elem register reductions (depth 4 not 16) and use
// native exp2 with v pre-scaled by log2e (1 mul + v_exp per element).

#define BB 64
#define II 1024
#define OO 1024
#define EPSF 1e-5f
#define LOG2E 1.44269504088896340736f

__device__ __forceinline__ float wave_sum(float v) {
    #pragma unroll
    for (int off = 32; off > 0; off >>= 1)
        v += __shfl_xor(v, off, 64);
    return v;
}
__device__ __forceinline__ void wave_sum2(float& a, float& b) {
    #pragma unroll
    for (int off = 32; off > 0; off >>= 1) {
        a += __shfl_xor(a, off, 64);   // two independent chains ->
        b += __shfl_xor(b, off, 64);   // scheduler interleaves them
    }
}
__device__ __forceinline__ float tree16(const float (&p)[16]) {
    float a0 = p[0]+p[1],  a1 = p[2]+p[3],  a2 = p[4]+p[5],  a3 = p[6]+p[7];
    float a4 = p[8]+p[9],  a5 = p[10]+p[11], a6 = p[12]+p[13], a7 = p[14]+p[15];
    float b0 = a0+a1, b1 = a2+a3, b2 = a4+a5, b3 = a6+a7;
    return (b0+b1)+(b2+b3);
}

// Cross-wave reduce of the 4 waves' ar[16] via LDS float-atomics
// (addr/4 = k*64+lane -> 2-way aliasing, free), then coalesced float4 store.
__device__ __forceinline__ void block_reduce_store(
    float* red, const float (&ar0)[16], const float (&ar1)[16], int lane,
    float* __restrict__ part_b0, float* __restrict__ part_b1)
{
    const int t = threadIdx.x;
    for (int r = t; r < 2048; r += 256) red[r] = 0.f;
    __syncthreads();
    #pragma unroll
    for (int k = 0; k < 16; k++) {
        atomicAdd(&red[k * 64 + lane],        ar0[k]);
        atomicAdd(&red[1024 + k * 64 + lane], ar1[k]);
    }
    __syncthreads();
    const int j  = t >> 6;
    const int ln = t & 63;
    float4 v0, v1;
    v0.x = red[(j*4+0)*64 + ln]; v0.y = red[(j*4+1)*64 + ln];
    v0.z = red[(j*4+2)*64 + ln]; v0.w = red[(j*4+3)*64 + ln];
    v1.x = red[1024 + (j*4+0)*64 + ln]; v1.y = red[1024 + (j*4+1)*64 + ln];
    v1.z = red[1024 + (j*4+2)*64 + ln]; v1.w = red[1024 + (j*4+3)*64 + ln];
    ((float4*)part_b0)[t] = v0;
    ((float4*)part_b1)[t] = v1;
}

template<int IBLKS>
__global__ __launch_bounds__(256, 4) void stage_k(
    const float* __restrict__ u, const float* __restrict__ w,
    const float* __restrict__ v, float* __restrict__ part)
{
    constexpr int IPB = II / IBLKS;   // i's per block
    constexpr int IW  = IPB / 4;      // i's per wave
    const int bg   = blockIdx.x / IBLKS;
    const int iblk = blockIdx.x % IBLKS;
    const int wave = threadIdx.x >> 6;
    const int lane = threadIdx.x & 63;
    const int b0 = bg * 2, b1 = b0 + 1;
    const float4* w4  = (const float4*)w;
    const float4* v40 = (const float4*)(v + b0 * OO);
    const float4* v41 = (const float4*)(v + b1 * OO);

    // v pre-scaled by log2e so the softmax logit feeds v_exp_f32 directly.
    float vv0[16], vv1[16];
    #pragma unroll
    for (int j = 0; j < 4; j++) {
        float4 a = v40[j * 64 + lane];
        float4 b = v41[j * 64 + lane];
        vv0[j*4+0]=a.x*LOG2E; vv0[j*4+1]=a.y*LOG2E;
        vv0[j*4+2]=a.z*LOG2E; vv0[j*4+3]=a.w*LOG2E;
        vv1[j*4+0]=b.x*LOG2E; vv1[j*4+1]=b.y*LOG2E;
        vv1[j*4+2]=b.z*LOG2E; vv1[j*4+3]=b.w*LOG2E;
    }
    float ar0[16], ar1[16];
    #pragma unroll
    for (int k = 0; k < 16; k++) { ar0[k] = 0.f; ar1[k] = 0.f; }

    const int i0 = iblk * IPB + wave * IW;
    #pragma unroll 2
    for (int ii = 0; ii < IW; ii++) {
        const int i = i0 + ii;
        const float ub0 = u[b0 * II + i];   // wave-uniform -> s_load
        const float ub1 = u[b1 * II + i];
        float wr[16];
        #pragma unroll
        for (int j = 0; j < 4; j++) {
            float4 t = w4[i * 256 + j * 64 + lane];
            wr[j*4+0]=t.x; wr[j*4+1]=t.y; wr[j*4+2]=t.z; wr[j*4+3]=t.w;
        }
        float p0[16], p1[16];
        #pragma unroll
        for (int k = 0; k < 16; k++) {     // |logit| <= ~0.45: no max-sub
            p0[k] = __builtin_amdgcn_exp2f((wr[k] * vv0[k]) * ub0);
            p1[k] = __builtin_amdgcn_exp2f((wr[k] * vv1[k]) * ub1);
        }
        float s0 = tree16(p0), s1 = tree16(p1);
        wave_sum2(s0, s1);
        const float q0 = ub0 / s0;         // fold u scalar into 1/sum
        const float q1 = ub1 / s1;
        #pragma unroll
        for (int k = 0; k < 16; k++) {
            ar0[k] = fmaf(wr[k] * p0[k], q0, ar0[k]);
            ar1[k] = fmaf(wr[k] * p1[k], q1, ar1[k]);
        }
    }
    __shared__ float red[2048];
    block_reduce_store(red, ar0, ar1, lane,
        part + ((size_t)iblk * BB + b0) * OO,
        part + ((size_t)iblk * BB + b1) * OO);
}

template<int IBLKS>
__global__ __launch_bounds__(256, 4) void gemm_k(
    const float* __restrict__ u, const float* __restrict__ w,
    float* __restrict__ part)
{
    constexpr int IPB = II / IBLKS;
    constexpr int IW  = IPB / 4;
    const int bg   = blockIdx.x / IBLKS;
    const int iblk = blockIdx.x % IBLKS;
    const int wave = threadIdx.x >> 6;
    const int lane = threadIdx.x & 63;
    const int b0 = bg * 2, b1 = b0 + 1;
    const float4* w4 = (const float4*)w;

    float ar0[16], ar1[16];
    #pragma unroll
    for (int k = 0; k < 16; k++) { ar0[k] = 0.f; ar1[k] = 0.f; }

    const int i0 = iblk * IPB + wave * IW;
    #pragma unroll 2
    for (int ii = 0; ii < IW; ii++) {
        const int i = i0 + ii;
        const float ub0 = u[b0 * II + i];
        const float ub1 = u[b1 * II + i];
        #pragma unroll
        for (int j = 0; j < 4; j++) {
            float4 t = w4[i * 256 + j * 64 + lane];
            ar0[j*4+0] = fmaf(ub0, t.x, ar0[j*4+0]);
            ar0[j*4+1] = fmaf(ub0, t.y, ar0[j*4+1]);
            ar0[j*4+2] = fmaf(ub0, t.z, ar0[j*4+2]);
            ar0[j*4+3] = fmaf(ub0, t.w, ar0[j*4+3]);
            ar1[j*4+0] = fmaf(ub1, t.x, ar1[j*4+0]);
            ar1[j*4+1] = fmaf(ub1, t.y, ar1[j*4+1]);
            ar1[j*4+2] = fmaf(ub1, t.z, ar1[j*4+2]);
            ar1[j*4+3] = fmaf(ub1, t.w, ar1[j*4+3]);
        }
    }
    __shared__ float red[2048];
    block_reduce_store(red, ar0, ar1, lane,
        part + ((size_t)iblk * BB + b0) * OO,
        part + ((size_t)iblk * BB + b1) * OO);
}

// Sum nblk partial slices, x = sum*scale + bias, squash row, emit:
// mode 0: vbuf = v   mode 1: vbuf += v   mode 2: out = v
__global__ __launch_bounds__(256) void reduce_squash(
    const float* __restrict__ part, const float* __restrict__ bias,
    float* __restrict__ vbuf, float* __restrict__ out,
    float scale, int mode, int nblk)
{
    const int b = blockIdx.x;
    const int t = threadIdx.x;
    const float4* p4 = (const float4*)part;

    float4 a = make_float4(0.f, 0.f, 0.f, 0.f);
    for (int k = 0; k < nblk; k++) {
        float4 p = p4[(size_t)(k * BB + b) * 256 + t];
        a.x += p.x; a.y += p.y; a.z += p.z; a.w += p.w;
    }
    float4 bb = ((const float4*)bias)[t];
    float4 x;
    x.x = fmaf(a.x, scale, bb.x); x.y = fmaf(a.y, scale, bb.y);
    x.z = fmaf(a.z, scale, bb.z); x.w = fmaf(a.w, scale, bb.w);

    float ss = x.x*x.x + x.y*x.y + x.z*x.z + x.w*x.w;
    ss = wave_sum(ss);
    __shared__ float red[4];
    if ((t & 63) == 0) red[t >> 6] = ss;
    __syncthreads();
    ss = red[0] + red[1] + red[2] + red[3];

    const float n  = sqrtf(ss);
    const float f  = ss / ((1.f + ss) * (n + EPSF));

    float4 vo;
    vo.x = x.x * f; vo.y = x.y * f; vo.z = x.z * f; vo.w = x.w * f;

    if (mode == 0) {
        ((float4*)(vbuf + b * OO))[t] = vo;
    } else if (mode == 1) {
        float4 pv = ((const float4*)(vbuf + b * OO))[t];
        pv.x += vo.x; pv.y += vo.y; pv.z += vo.z; pv.w += vo.w;
        ((float4*)(vbuf + b * OO))[t] = pv;
    } else {
        ((float4*)(out + b * OO))[t] = vo;
    }
}

template<int IBLKS>
static void run_pipeline(const float* u, const float* w, const float* bias,
                         float* out, void* d_ws, hipStream_t stream)
{
    float* part = (float*)d_ws;
    float* vbuf = part + (size_t)IBLKS * BB * OO;
    dim3 g((BB / 2) * IBLKS), blk(256);
    // v1 = squash((u@w)/O + bias)
    gemm_k<IBLKS><<<g, blk, 0, stream>>>(u, w, part);
    reduce_squash<<<dim3(BB), blk, 0, stream>>>(part, bias, vbuf, out,
                                                1.0f / (float)OO, 0, IBLKS);
    // vsum = v1 + squash(s2 + bias),  s2 via softmax(u*w*v1)
    stage_k<IBLKS><<<g, blk, 0, stream>>>(u, w, vbuf, part);
    reduce_squash<<<dim3(BB), blk, 0, stream>>>(part, bias, vbuf, out,
                                                1.0f, 1, IBLKS);
    // out = squash(s3 + bias),  s3 via softmax(u*w*vsum)
    stage_k<IBLKS><<<g, blk, 0, stream>>>(u, w, vbuf, part);
    reduce_squash<<<dim3(BB), blk, 0, stream>>>(part, bias, vbuf, out,
                                                1.0f, 2, IBLKS);
}

extern "C" void kernel_launch(void* const* d_in, const int* in_sizes, int n_in,
                              void* d_out, int out_size, void* d_ws, size_t ws_size,
                              hipStream_t stream) {
    (void)in_sizes; (void)n_in; (void)out_size;
    const float* u    = (const float*)d_in[0];
    const float* w    = (const float*)d_in[1];
    const float* bias = (const float*)d_in[2];
    float* out = (float*)d_out;

    const size_t row = (size_t)BB * OO * sizeof(float);  // 256 KB
    if      (ws_size >= 33 * row) run_pipeline<32>(u, w, bias, out, d_ws, stream);
    else if (ws_size >= 17 * row) run_pipeline<16>(u, w, bias, out, d_ws, stream);
    else if (ws_size >=  9 * row) run_pipeline<8>(u, w, bias, out, d_ws, stream);
    else                          run_pipeline<4>(u, w, bias, out, d_ws, stream);
}